// Round 3
// baseline (918.849 us; speedup 1.0000x reference)
//
#include <hip/hip_runtime.h>

#define FEAT 32
#define BIN_NODES 128       // nodes per bin -> 16 KB LDS accumulator
#define BIN_SHIFT 7
#define TILE_EDGES 8192     // edges per binning block
#define SRC_BITS 20
#define SRC_MASK 0xFFFFF

// --- Detect whether edge_index is int64 (all odd int32 words zero) or int32.
__global__ void detect_int64_kernel(const int* __restrict__ raw, int* flag) {
    __shared__ int nonzero;
    if (threadIdx.x == 0) nonzero = 0;
    __syncthreads();
    int v = raw[2 * threadIdx.x + 1];
    if (v != 0) atomicAdd(&nonzero, 1);
    __syncthreads();
    if (threadIdx.x == 0) *flag = (nonzero == 0) ? 1 : 0;
}

__device__ __forceinline__ int load_idx(const void* raw, int f, long long i) {
    return f ? (int)((const long long*)raw)[i] : ((const int*)raw)[i];
}

// Phase A: per-(block,bin) histogram. mat layout: mat[k*nb + b] (block-major).
__global__ void binA_kernel(const void* __restrict__ raw, const int* __restrict__ flag,
                            int* __restrict__ mat, int e, int nb) {
    extern __shared__ int hist[];  // nb ints
    int t = threadIdx.x;
    for (int i = t; i < nb; i += 256) hist[i] = 0;
    __syncthreads();
    int f = *flag;
    long long base = (long long)blockIdx.x * TILE_EDGES;
    int cnt = (int)min((long long)TILE_EDGES, (long long)e - base);
    for (int i = t; i < cnt; i += 256) {
        int d = load_idx(raw, f, (long long)e + base + i);
        atomicAdd(&hist[d >> BIN_SHIFT], 1);
    }
    __syncthreads();
    for (int b = t; b < nb; b += 256) mat[blockIdx.x * nb + b] = hist[b];
}

// logical L = b*nblk + k  (bin-major scan order) <-> physical p = k*nb + b
__device__ __forceinline__ int l2p(int L, int nb, int nblk) {
    int b = L / nblk;
    int k = L - b * nblk;
    return k * nb + b;
}

__global__ void scan1_kernel(int* __restrict__ mat, int* __restrict__ bsum,
                             int M, int nb, int nblk) {
    __shared__ int sd[256];
    int t = threadIdx.x;
    int L = blockIdx.x * 256 + t;
    int p = 0, v = 0;
    if (L < M) { p = l2p(L, nb, nblk); v = mat[p]; }
    sd[t] = v;
    __syncthreads();
    for (int off = 1; off < 256; off <<= 1) {
        int add = (t >= off) ? sd[t - off] : 0;
        __syncthreads();
        sd[t] += add;
        __syncthreads();
    }
    if (L < M) mat[p] = sd[t] - v;         // exclusive within block
    if (t == 255) bsum[blockIdx.x] = sd[t];
}

__global__ void scan2_kernel(int* __restrict__ bsum, int nbks) {  // single block, 1024 thr
    __shared__ int sd[1024];
    int t = threadIdx.x;
    int v = (t < nbks) ? bsum[t] : 0;
    sd[t] = v;
    __syncthreads();
    for (int off = 1; off < 1024; off <<= 1) {
        int add = (t >= off) ? sd[t - off] : 0;
        __syncthreads();
        sd[t] += add;
        __syncthreads();
    }
    if (t < nbks) bsum[t] = sd[t] - v;
}

__global__ void scan3_kernel(int* __restrict__ mat, const int* __restrict__ bsum,
                             int M, int nb, int nblk) {
    int L = blockIdx.x * 256 + threadIdx.x;
    if (L < M) mat[l2p(L, nb, nblk)] += bsum[L >> 8];
}

// Phase C: scatter records grouped by bin per block (writes merge in own-XCD L2).
// rec = src | (dst_local << SRC_BITS), 4 bytes.
__global__ void binC_kernel(const void* __restrict__ raw, const int* __restrict__ flag,
                            const int* __restrict__ mat, int* __restrict__ recs,
                            int e, int nb) {
    extern __shared__ int cur[];  // nb cursors
    int t = threadIdx.x;
    for (int i = t; i < nb; i += 256) cur[i] = mat[blockIdx.x * nb + i];
    __syncthreads();
    int f = *flag;
    long long base = (long long)blockIdx.x * TILE_EDGES;
    int cnt = (int)min((long long)TILE_EDGES, (long long)e - base);
    for (int i = t; i < cnt; i += 256) {
        long long ei = base + i;
        int s = load_idx(raw, f, ei);
        int d = load_idx(raw, f, (long long)e + ei);
        int b = d >> BIN_SHIFT;
        int pos = atomicAdd(&cur[b], 1);
        recs[pos] = s | ((d & (BIN_NODES - 1)) << SRC_BITS);
    }
}

// Degrees via per-bin LDS histogram -> dis = rsqrt(deg+1). No global atomics.
__global__ void degdis_kernel(const int* __restrict__ recs, const int* __restrict__ mat,
                              float* __restrict__ dis, int e, int n, int nb) {
    __shared__ int cnt[BIN_NODES];
    int b = blockIdx.x, t = threadIdx.x;
    if (t < BIN_NODES) cnt[t] = 0;
    __syncthreads();
    int start = mat[b];                        // physical row k=0 = bin starts
    int end = (b + 1 < nb) ? mat[b + 1] : e;
    for (int i = start + t; i < end; i += 256) atomicAdd(&cnt[recs[i] >> SRC_BITS], 1);
    __syncthreads();
    int node = b * BIN_NODES + t;
    if (t < BIN_NODES && node < n) dis[node] = rsqrtf((float)cnt[t] + 1.0f);
}

// h = act(in) @ W   (8 nodes x 32 lanes per block, W in LDS, shfl-broadcast)
__global__ void matmul_kernel(const float* __restrict__ in, const float* __restrict__ W,
                              float* __restrict__ h, int n, int relu_in) {
    __shared__ float Wl[FEAT * FEAT];
    int tid = threadIdx.x;
    for (int i = tid; i < FEAT * FEAT; i += 256) Wl[i] = W[i];
    __syncthreads();
    int node = blockIdx.x * 8 + (tid >> 5);
    int j = tid & 31;
    if (node >= n) return;
    float xv = in[node * FEAT + j];
    if (relu_in) xv = fmaxf(xv, 0.0f);
    float sum = 0.0f;
#pragma unroll
    for (int k = 0; k < FEAT; ++k) sum = fmaf(__shfl(xv, k, 32), Wl[k * FEAT + j], sum);
    h[node * FEAT + j] = sum;
}

// Per-bin aggregation into a 16 KB LDS accumulator. Accumulates sum over edges of
// dis[src]*h[src]; dis[dst] factored out to the writeout. Self-loop+bias+relu fused.
__global__ void agg_kernel(const int* __restrict__ recs, const int* __restrict__ mat,
                           const float* __restrict__ h, const float* __restrict__ dis,
                           const float* __restrict__ bias, float* __restrict__ out,
                           int e, int n, int nb, int relu_out) {
    __shared__ float accS[BIN_NODES * FEAT];  // 16 KB
    int b = blockIdx.x, t = threadIdx.x;
    for (int i = t; i < BIN_NODES * FEAT; i += 256) accS[i] = 0.0f;
    __syncthreads();
    int start = mat[b];
    int end = (b + 1 < nb) ? mat[b + 1] : e;
    int lane = t & 63, wave = t >> 6;
    int j = lane & 31, half = lane >> 5;
    for (int i = start + wave * 64; i < end; i += 256) {
        int c = end - i;
        if (c > 64) c = 64;
        int rec = 0;
        float dw = 0.0f;  // 0-weight for pad lanes -> contributes exactly 0
        if (lane < c) { rec = recs[i + lane]; dw = dis[rec & SRC_MASK]; }
        int kb = half * 32;
#pragma unroll 2
        for (int k = 0; k < 32; k += 4) {
            int   r0 = __shfl(rec, kb + k + 0, 64); float w0 = __shfl(dw, kb + k + 0, 64);
            int   r1 = __shfl(rec, kb + k + 1, 64); float w1 = __shfl(dw, kb + k + 1, 64);
            int   r2 = __shfl(rec, kb + k + 2, 64); float w2 = __shfl(dw, kb + k + 2, 64);
            int   r3 = __shfl(rec, kb + k + 3, 64); float w3 = __shfl(dw, kb + k + 3, 64);
            float v0 = h[(r0 & SRC_MASK) * FEAT + j];
            float v1 = h[(r1 & SRC_MASK) * FEAT + j];
            float v2 = h[(r2 & SRC_MASK) * FEAT + j];
            float v3 = h[(r3 & SRC_MASK) * FEAT + j];
            atomicAdd(&accS[(r0 >> SRC_BITS) * FEAT + j], v0 * w0);
            atomicAdd(&accS[(r1 >> SRC_BITS) * FEAT + j], v1 * w1);
            atomicAdd(&accS[(r2 >> SRC_BITS) * FEAT + j], v2 * w2);
            atomicAdd(&accS[(r3 >> SRC_BITS) * FEAT + j], v3 * w3);
        }
    }
    __syncthreads();
    // writeout: out = act( dis[d] * accS_row + dis[d]^2 * h[d] + bias )
    int jj = t & 31;
    for (int r = (t >> 5); r < BIN_NODES; r += 8) {
        int node = b * BIN_NODES + r;
        if (node >= n) break;
        float dn = dis[node];
        float val = fmaf(accS[r * FEAT + jj], dn,
                         fmaf(h[node * FEAT + jj], dn * dn, bias[jj]));
        if (relu_out) val = fmaxf(val, 0.0f);
        out[node * FEAT + jj] = val;
    }
}

extern "C" void kernel_launch(void* const* d_in, const int* in_sizes, int n_in,
                              void* d_out, int out_size, void* d_ws, size_t ws_size,
                              hipStream_t stream) {
    const float* x = (const float*)d_in[0];
    const void* eidx_raw = d_in[1];
    const float* W1 = (const float*)d_in[2];
    const float* b1 = (const float*)d_in[3];
    const float* W2 = (const float*)d_in[4];
    const float* b2 = (const float*)d_in[5];
    float* out = (float*)d_out;

    const int n = in_sizes[0] / FEAT;           // 100000
    const int e = in_sizes[1] / 2;              // 1600000
    const int nb = (n + BIN_NODES - 1) / BIN_NODES;      // 782
    const int nblk = (e + TILE_EDGES - 1) / TILE_EDGES;  // 196
    const int M = nb * nblk;                    // scan length
    const int nbks = (M + 255) / 256;           // scan1 blocks (<=1024 required)

    // Workspace layout (256B-aligned slices), ~33 MB
    char* ws = (char*)d_ws;
    size_t off = 0;
    auto alloc = [&](size_t bytes) { char* p = ws + off; off = (off + bytes + 255) & ~(size_t)255; return p; };
    int*   flag = (int*)  alloc(256);
    int*   mat  = (int*)  alloc((size_t)M * 4);
    int*   bsum = (int*)  alloc((size_t)nbks * 4);
    int*   recs = (int*)  alloc((size_t)e * 4);
    float* dis  = (float*)alloc((size_t)n * 4);
    float* h    = (float*)alloc((size_t)n * FEAT * 4);
    float* acc1 = (float*)alloc((size_t)n * FEAT * 4);

    const size_t lds_bins = (size_t)nb * 4;

    // CSR-by-bin build (no global atomics anywhere)
    detect_int64_kernel<<<1, 256, 0, stream>>>((const int*)eidx_raw, flag);
    binA_kernel<<<nblk, 256, lds_bins, stream>>>(eidx_raw, flag, mat, e, nb);
    scan1_kernel<<<nbks, 256, 0, stream>>>(mat, bsum, M, nb, nblk);
    scan2_kernel<<<1, 1024, 0, stream>>>(bsum, nbks);
    scan3_kernel<<<nbks, 256, 0, stream>>>(mat, bsum, M, nb, nblk);
    binC_kernel<<<nblk, 256, lds_bins, stream>>>(eidx_raw, flag, mat, recs, e, nb);
    degdis_kernel<<<nb, 256, 0, stream>>>(recs, mat, dis, e, n, nb);

    // Layer 1
    matmul_kernel<<<(n + 7) / 8, 256, 0, stream>>>(x, W1, h, n, 0);
    agg_kernel<<<nb, 256, 0, stream>>>(recs, mat, h, dis, b1, acc1, e, n, nb, 0);

    // Layer 2 (relu on read of acc1; final relu fused into writeout)
    matmul_kernel<<<(n + 7) / 8, 256, 0, stream>>>(acc1, W2, h, n, 1);
    agg_kernel<<<nb, 256, 0, stream>>>(recs, mat, h, dis, b2, out, e, n, nb, 1);
}

// Round 4
// 274.944 us; speedup vs baseline: 3.3420x; 3.3420x over previous
//
#include <hip/hip_runtime.h>

#define FEAT 32
#define BIN_NODES 128
#define BIN_SHIFT 7
#define TILE_EDGES 8192
#define SRC_BITS 20
#define SRC_MASK 0xFFFFF

// --- Detect whether edge_index is int64 (all odd int32 words zero) or int32.
__global__ void detect_int64_kernel(const int* __restrict__ raw, int* flag) {
    __shared__ int nonzero;
    if (threadIdx.x == 0) nonzero = 0;
    __syncthreads();
    int v = raw[2 * threadIdx.x + 1];
    if (v != 0) atomicAdd(&nonzero, 1);
    __syncthreads();
    if (threadIdx.x == 0) *flag = (nonzero == 0) ? 1 : 0;
}

__device__ __forceinline__ int load_idx(const void* raw, int f, long long i) {
    return f ? (int)((const long long*)raw)[i] : ((const int*)raw)[i];
}

// Phase A: per-(tile,bin) histogram. mat layout: mat[k*nb + b] (tile-major).
__global__ void binA_kernel(const void* __restrict__ raw, const int* __restrict__ flag,
                            int* __restrict__ mat, int e, int nb) {
    extern __shared__ int hist[];
    int t = threadIdx.x;
    for (int i = t; i < nb; i += 256) hist[i] = 0;
    __syncthreads();
    int f = *flag;
    long long base = (long long)blockIdx.x * TILE_EDGES;
    int cnt = (int)min((long long)TILE_EDGES, (long long)e - base);
    for (int i = t; i < cnt; i += 256) {
        int d = load_idx(raw, f, (long long)e + base + i);
        atomicAdd(&hist[d >> BIN_SHIFT], 1);
    }
    __syncthreads();
    for (int b = t; b < nb; b += 256) mat[blockIdx.x * nb + b] = hist[b];
}

// logical L = b*nblk + k (bin-major) <-> physical p = k*nb + b
__device__ __forceinline__ int l2p(int L, int nb, int nblk) {
    int b = L / nblk;
    int k = L - b * nblk;
    return k * nb + b;
}

__global__ void scan1_kernel(int* __restrict__ mat, int* __restrict__ bsum,
                             int M, int nb, int nblk) {
    __shared__ int sd[256];
    int t = threadIdx.x;
    int L = blockIdx.x * 256 + t;
    int p = 0, v = 0;
    if (L < M) { p = l2p(L, nb, nblk); v = mat[p]; }
    sd[t] = v;
    __syncthreads();
    for (int off = 1; off < 256; off <<= 1) {
        int add = (t >= off) ? sd[t - off] : 0;
        __syncthreads();
        sd[t] += add;
        __syncthreads();
    }
    if (L < M) mat[p] = sd[t] - v;
    if (t == 255) bsum[blockIdx.x] = sd[t];
}

__global__ void scan2_kernel(int* __restrict__ bsum, int nbks) {
    __shared__ int sd[1024];
    int t = threadIdx.x;
    int v = (t < nbks) ? bsum[t] : 0;
    sd[t] = v;
    __syncthreads();
    for (int off = 1; off < 1024; off <<= 1) {
        int add = (t >= off) ? sd[t - off] : 0;
        __syncthreads();
        sd[t] += add;
        __syncthreads();
    }
    if (t < nbks) bsum[t] = sd[t] - v;
}

__global__ void scan3_kernel(int* __restrict__ mat, const int* __restrict__ bsum,
                             int M, int nb, int nblk) {
    int L = blockIdx.x * 256 + threadIdx.x;
    if (L < M) mat[l2p(L, nb, nblk)] += bsum[L >> 8];
}

// Phase C: scatter packed records grouped by bin. rec = src | dst_local<<20.
__global__ void binC_kernel(const void* __restrict__ raw, const int* __restrict__ flag,
                            const int* __restrict__ mat, int* __restrict__ packed,
                            int e, int nb) {
    extern __shared__ int cur[];
    int t = threadIdx.x;
    for (int i = t; i < nb; i += 256) cur[i] = mat[blockIdx.x * nb + i];
    __syncthreads();
    int f = *flag;
    long long base = (long long)blockIdx.x * TILE_EDGES;
    int cnt = (int)min((long long)TILE_EDGES, (long long)e - base);
    for (int i = t; i < cnt; i += 256) {
        long long ei = base + i;
        int s = load_idx(raw, f, ei);
        int d = load_idx(raw, f, (long long)e + ei);
        int b = d >> BIN_SHIFT;
        int pos = atomicAdd(&cur[b], 1);
        packed[pos] = s | ((d & (BIN_NODES - 1)) << SRC_BITS);
    }
}

// Per-bin degree count + exclusive scan -> per-node row_start, deg, dis.
__global__ void degdis_kernel(const int* __restrict__ packed, const int* __restrict__ mat,
                              float* __restrict__ dis, int* __restrict__ row_start,
                              int* __restrict__ deg, int e, int n, int nb) {
    __shared__ int cnt[BIN_NODES];
    __shared__ int exc[BIN_NODES];
    int b = blockIdx.x, t = threadIdx.x;
    if (t < BIN_NODES) cnt[t] = 0;
    __syncthreads();
    int start = mat[b];
    int end = (b + 1 < nb) ? mat[b + 1] : e;
    for (int i = start + t; i < end; i += 256) atomicAdd(&cnt[packed[i] >> SRC_BITS], 1);
    __syncthreads();
    if (t < BIN_NODES) exc[t] = cnt[t];
    __syncthreads();
    for (int off = 1; off < BIN_NODES; off <<= 1) {
        int v = 0;
        if (t < BIN_NODES && t >= off) v = exc[t - off];
        __syncthreads();
        if (t < BIN_NODES) exc[t] += v;
        __syncthreads();
    }
    int node = b * BIN_NODES + t;
    if (t < BIN_NODES && node < n) {
        int c = cnt[t];
        dis[node] = rsqrtf((float)c + 1.0f);
        deg[node] = c;
        row_start[node] = start + exc[t] - c;  // inclusive->exclusive
    }
}

// Counting-sort records within each bin into per-node CSR order, fusing norm.
// Output rec = (src, norm) int2. Writes land in the bin's contiguous 16KB region.
__global__ void sortfill_kernel(const int* __restrict__ packed, const int* __restrict__ mat,
                                const float* __restrict__ dis, const int* __restrict__ row_start,
                                int2* __restrict__ recs2, int e, int n, int nb) {
    __shared__ int cur[BIN_NODES];
    __shared__ float dloc[BIN_NODES];
    int b = blockIdx.x, t = threadIdx.x;
    int nodebase = b * BIN_NODES;
    if (t < BIN_NODES) {
        int node = nodebase + t;
        cur[t] = (node < n) ? row_start[node] : 0;
        dloc[t] = (node < n) ? dis[node] : 0.0f;
    }
    __syncthreads();
    int start = mat[b];
    int end = (b + 1 < nb) ? mat[b + 1] : e;
    for (int i = start + t; i < end; i += 256) {
        int rec = packed[i];
        int s = rec & SRC_MASK;
        int dl = rec >> SRC_BITS;
        float nm = dis[s] * dloc[dl];
        int pos = atomicAdd(&cur[dl], 1);
        recs2[pos] = make_int2(s, __float_as_int(nm));
    }
}

// h = act(in) @ W   (8 nodes x 32 lanes per block, W in LDS, shfl-broadcast)
__global__ void matmul_kernel(const float* __restrict__ in, const float* __restrict__ W,
                              float* __restrict__ h, int n, int relu_in) {
    __shared__ float Wl[FEAT * FEAT];
    int tid = threadIdx.x;
    for (int i = tid; i < FEAT * FEAT; i += 256) Wl[i] = W[i];
    __syncthreads();
    int node = blockIdx.x * 8 + (tid >> 5);
    int j = tid & 31;
    if (node >= n) return;
    float xv = in[node * FEAT + j];
    if (relu_in) xv = fmaxf(xv, 0.0f);
    float sum = 0.0f;
#pragma unroll
    for (int k = 0; k < FEAT; ++k) sum = fmaf(__shfl(xv, k, 32), Wl[k * FEAT + j], sum);
    h[node * FEAT + j] = sum;
}

// Pull aggregation: 32 lanes/node = 4 record-slots x 8 feature-lanes (float4).
// Each step issues one float4 gather covering 4 records/node (8/wave); 8
// independent predicated steps per window -> deep MLP, no shfl/LDS on the path.
__global__ __launch_bounds__(256, 4)
void pull_kernel(const int2* __restrict__ recs2, const int* __restrict__ row_start,
                 const int* __restrict__ deg_arr, const float* __restrict__ h,
                 const float* __restrict__ dis, const float* __restrict__ bias,
                 float* __restrict__ out, int n, int relu_out) {
    int t = threadIdx.x;
    int node = blockIdx.x * 8 + (t >> 5);
    if (node >= n) return;
    int l32 = t & 31;
    int sub = l32 >> 3;   // record slot 0..3
    int fb = l32 & 7;     // feature block (float4)
    int start = row_start[node];
    int deg = deg_arr[node];
    const float4* h4 = (const float4*)h;
    float4 sum = make_float4(0.0f, 0.0f, 0.0f, 0.0f);
    for (int r0 = 0; r0 < deg; r0 += 32) {
#pragma unroll
        for (int w = 0; w < 8; ++w) {
            int r = r0 + w * 4 + sub;
            if (r < deg) {
                int2 rec = recs2[start + r];
                float nm = __int_as_float(rec.y);
                float4 v = h4[(size_t)rec.x * 8 + fb];
                sum.x = fmaf(v.x, nm, sum.x);
                sum.y = fmaf(v.y, nm, sum.y);
                sum.z = fmaf(v.z, nm, sum.z);
                sum.w = fmaf(v.w, nm, sum.w);
            }
        }
    }
    // reduce across the 4 record slots (xor 8, 16 stays within the 32-group)
    sum.x += __shfl_xor(sum.x, 8, 64);  sum.y += __shfl_xor(sum.y, 8, 64);
    sum.z += __shfl_xor(sum.z, 8, 64);  sum.w += __shfl_xor(sum.w, 8, 64);
    sum.x += __shfl_xor(sum.x, 16, 64); sum.y += __shfl_xor(sum.y, 16, 64);
    sum.z += __shfl_xor(sum.z, 16, 64); sum.w += __shfl_xor(sum.w, 16, 64);
    if (sub == 0) {
        float dn = dis[node];
        float dd = dn * dn;
        float4 hv = h4[(size_t)node * 8 + fb];
        float4 bv = ((const float4*)bias)[fb];
        float4 val;
        val.x = fmaf(hv.x, dd, bv.x) + sum.x;
        val.y = fmaf(hv.y, dd, bv.y) + sum.y;
        val.z = fmaf(hv.z, dd, bv.z) + sum.z;
        val.w = fmaf(hv.w, dd, bv.w) + sum.w;
        if (relu_out) {
            val.x = fmaxf(val.x, 0.0f); val.y = fmaxf(val.y, 0.0f);
            val.z = fmaxf(val.z, 0.0f); val.w = fmaxf(val.w, 0.0f);
        }
        ((float4*)out)[(size_t)node * 8 + fb] = val;
    }
}

extern "C" void kernel_launch(void* const* d_in, const int* in_sizes, int n_in,
                              void* d_out, int out_size, void* d_ws, size_t ws_size,
                              hipStream_t stream) {
    const float* x = (const float*)d_in[0];
    const void* eidx_raw = d_in[1];
    const float* W1 = (const float*)d_in[2];
    const float* b1 = (const float*)d_in[3];
    const float* W2 = (const float*)d_in[4];
    const float* b2 = (const float*)d_in[5];
    float* out = (float*)d_out;

    const int n = in_sizes[0] / FEAT;                    // 100000
    const int e = in_sizes[1] / 2;                       // 1600000
    const int nb = (n + BIN_NODES - 1) / BIN_NODES;      // 782
    const int nblk = (e + TILE_EDGES - 1) / TILE_EDGES;  // 196
    const int M = nb * nblk;
    const int nbks = (M + 255) / 256;                    // 599 <= 1024

    // Workspace (256B-aligned). `packed` aliases `h` (dead before matmul writes h).
    char* ws = (char*)d_ws;
    size_t off = 0;
    auto alloc = [&](size_t bytes) { char* p = ws + off; off = (off + bytes + 255) & ~(size_t)255; return p; };
    int*   flag      = (int*)  alloc(256);
    int*   mat       = (int*)  alloc((size_t)M * 4);
    int*   bsum      = (int*)  alloc((size_t)nbks * 4);
    float* dis       = (float*)alloc((size_t)n * 4);
    int*   row_start = (int*)  alloc((size_t)n * 4);
    int*   deg       = (int*)  alloc((size_t)n * 4);
    int2*  recs2     = (int2*) alloc((size_t)e * 8);
    float* h         = (float*)alloc((size_t)n * FEAT * 4);
    float* acc1      = (float*)alloc((size_t)n * FEAT * 4);
    int*   packed    = (int*)h;   // e*4 = 6.4MB <= 12.8MB, lifetime ends before matmul1

    const size_t lds_bins = (size_t)nb * 4;
    const int gNode = (n + 7) / 8;

    // CSR build
    detect_int64_kernel<<<1, 256, 0, stream>>>((const int*)eidx_raw, flag);
    binA_kernel<<<nblk, 256, lds_bins, stream>>>(eidx_raw, flag, mat, e, nb);
    scan1_kernel<<<nbks, 256, 0, stream>>>(mat, bsum, M, nb, nblk);
    scan2_kernel<<<1, 1024, 0, stream>>>(bsum, nbks);
    scan3_kernel<<<nbks, 256, 0, stream>>>(mat, bsum, M, nb, nblk);
    binC_kernel<<<nblk, 256, lds_bins, stream>>>(eidx_raw, flag, mat, packed, e, nb);
    degdis_kernel<<<nb, 256, 0, stream>>>(packed, mat, dis, row_start, deg, e, n, nb);
    sortfill_kernel<<<nb, 256, 0, stream>>>(packed, mat, dis, row_start, recs2, e, n, nb);

    // Layer 1
    matmul_kernel<<<gNode, 256, 0, stream>>>(x, W1, h, n, 0);
    pull_kernel<<<gNode, 256, 0, stream>>>(recs2, row_start, deg, h, dis, b1, acc1, n, 0);

    // Layer 2 (relu applied on read of acc1; final relu fused in pull writeout)
    matmul_kernel<<<gNode, 256, 0, stream>>>(acc1, W2, h, n, 1);
    pull_kernel<<<gNode, 256, 0, stream>>>(recs2, row_start, deg, h, dis, b2, out, n, 1);
}

// Round 5
// 256.557 us; speedup vs baseline: 3.5815x; 1.0717x over previous
//
#include <hip/hip_runtime.h>

#define FEAT 32
#define BIN_NODES 128
#define BIN_SHIFT 7
#define TILE_EDGES 8192
#define SRC_BITS 20
#define SRC_MASK 0xFFFFF

// Block-local int64-vs-int32 detection: odd 32-bit words of an int64 index
// array (values < 2^31) are all zero; for int32 they are node ids (P(all 256
// sampled == 0) ~ 1e-1280). nz must point to shared memory.
__device__ __forceinline__ int block_detect_int64(const int* __restrict__ raw32, int* nz) {
    if (threadIdx.x == 0) *nz = 0;
    __syncthreads();
    if (raw32[2 * threadIdx.x + 1] != 0) *nz = 1;
    __syncthreads();
    return (*nz == 0) ? 1 : 0;
}

__device__ __forceinline__ int load_idx(const void* raw, int f, long long i) {
    return f ? (int)((const long long*)raw)[i] : ((const int*)raw)[i];
}

// Phase A: per-(tile,bin) histogram. mat layout: mat[k*nb + b] (tile-major).
__global__ void binA_kernel(const void* __restrict__ raw, int* __restrict__ mat,
                            int e, int nb) {
    extern __shared__ int hist[];  // nb + 1
    int t = threadIdx.x;
    for (int i = t; i < nb; i += 256) hist[i] = 0;
    int f = block_detect_int64((const int*)raw, &hist[nb]);  // syncs cover zeroing
    long long base = (long long)blockIdx.x * TILE_EDGES;
    int cnt = (int)min((long long)TILE_EDGES, (long long)e - base);
    for (int i = t; i < cnt; i += 256) {
        int d = load_idx(raw, f, (long long)e + base + i);
        atomicAdd(&hist[d >> BIN_SHIFT], 1);
    }
    __syncthreads();
    for (int b = t; b < nb; b += 256) mat[blockIdx.x * nb + b] = hist[b];
}

// logical L = b*nblk + k (bin-major) <-> physical p = k*nb + b
__device__ __forceinline__ int l2p(int L, int nb, int nblk) {
    int b = L / nblk;
    int k = L - b * nblk;
    return k * nb + b;
}

__global__ void scan1_kernel(int* __restrict__ mat, int* __restrict__ bsum,
                             int M, int nb, int nblk) {
    __shared__ int sd[256];
    int t = threadIdx.x;
    int L = blockIdx.x * 256 + t;
    int p = 0, v = 0;
    if (L < M) { p = l2p(L, nb, nblk); v = mat[p]; }
    sd[t] = v;
    __syncthreads();
    for (int off = 1; off < 256; off <<= 1) {
        int add = (t >= off) ? sd[t - off] : 0;
        __syncthreads();
        sd[t] += add;
        __syncthreads();
    }
    if (L < M) mat[p] = sd[t] - v;   // exclusive within scan-block
    if (t == 255) bsum[blockIdx.x] = sd[t];
}

__global__ void scan2_kernel(int* __restrict__ bsum, int nbks) {
    __shared__ int sd[1024];
    int t = threadIdx.x;
    int v = (t < nbks) ? bsum[t] : 0;
    sd[t] = v;
    __syncthreads();
    for (int off = 1; off < 1024; off <<= 1) {
        int add = (t >= off) ? sd[t - off] : 0;
        __syncthreads();
        sd[t] += add;
        __syncthreads();
    }
    if (t < nbks) bsum[t] = sd[t] - v;  // exclusive scan-block offsets
}

// Phase C: scatter packed records grouped by bin (bsum correction inlined).
// rec = src | dst_local<<20.
__global__ void binC_kernel(const void* __restrict__ raw, const int* __restrict__ mat,
                            const int* __restrict__ bsum, int* __restrict__ packed,
                            int e, int nb, int nblk) {
    extern __shared__ int cur[];  // nb + 1
    int t = threadIdx.x;
    int f = block_detect_int64((const int*)raw, &cur[nb]);
    for (int i = t; i < nb; i += 256)
        cur[i] = mat[blockIdx.x * nb + i] + bsum[(i * nblk + blockIdx.x) >> 8];
    __syncthreads();
    long long base = (long long)blockIdx.x * TILE_EDGES;
    int cnt = (int)min((long long)TILE_EDGES, (long long)e - base);
    for (int i = t; i < cnt; i += 256) {
        long long ei = base + i;
        int s = load_idx(raw, f, ei);
        int d = load_idx(raw, f, (long long)e + ei);
        int b = d >> BIN_SHIFT;
        int pos = atomicAdd(&cur[b], 1);
        packed[pos] = s | ((d & (BIN_NODES - 1)) << SRC_BITS);
    }
}

// Fused: per-bin degree count + LDS scan -> dis/deg/row_start, then counting-sort
// records to per-node CSR order. Records out = src only (4B).
__global__ void degsort_kernel(const int* __restrict__ packed, const int* __restrict__ mat,
                               const int* __restrict__ bsum, float* __restrict__ dis,
                               int* __restrict__ row_start, int* __restrict__ deg,
                               int* __restrict__ recs, int e, int n, int nb, int nblk) {
    __shared__ int cnt[BIN_NODES], exc[BIN_NODES], cur[BIN_NODES];
    int b = blockIdx.x, t = threadIdx.x;
    if (t < BIN_NODES) cnt[t] = 0;
    __syncthreads();
    int start = mat[b] + bsum[(b * nblk) >> 8];   // logical L = b*nblk, physical mat[b]
    int end = (b + 1 < nb) ? (mat[b + 1] + bsum[((b + 1) * nblk) >> 8]) : e;
    for (int i = start + t; i < end; i += 256) atomicAdd(&cnt[packed[i] >> SRC_BITS], 1);
    __syncthreads();
    if (t < BIN_NODES) exc[t] = cnt[t];
    __syncthreads();
    for (int off = 1; off < BIN_NODES; off <<= 1) {
        int v = 0;
        if (t < BIN_NODES && t >= off) v = exc[t - off];
        __syncthreads();
        if (t < BIN_NODES) exc[t] += v;
        __syncthreads();
    }
    if (t < BIN_NODES) {
        int node = b * BIN_NODES + t;
        int rs = start + exc[t] - cnt[t];
        cur[t] = rs;
        if (node < n) {
            dis[node] = rsqrtf((float)cnt[t] + 1.0f);
            deg[node] = cnt[t];
            row_start[node] = rs;
        }
    }
    __syncthreads();
    for (int i = start + t; i < end; i += 256) {
        int rec = packed[i];
        int pos = atomicAdd(&cur[rec >> SRC_BITS], 1);
        recs[pos] = rec & SRC_MASK;
    }
}

// h~ = dis * (act(in) @ W)   (8 nodes x 32 lanes per block, W in LDS)
__global__ void matmul_kernel(const float* __restrict__ in, const float* __restrict__ W,
                              const float* __restrict__ dis, float* __restrict__ h,
                              int n, int relu_in) {
    __shared__ float Wl[FEAT * FEAT];
    int tid = threadIdx.x;
    for (int i = tid; i < FEAT * FEAT; i += 256) Wl[i] = W[i];
    __syncthreads();
    int node = blockIdx.x * 8 + (tid >> 5);
    int j = tid & 31;
    if (node >= n) return;
    float xv = in[node * FEAT + j];
    if (relu_in) xv = fmaxf(xv, 0.0f);
    float sum = 0.0f;
#pragma unroll
    for (int k = 0; k < FEAT; ++k) sum = fmaf(__shfl(xv, k, 32), Wl[k * FEAT + j], sum);
    h[node * FEAT + j] = dis[node] * sum;
}

// Pull: out[d] = act( dis[d] * (sum_{s in N(d)} h~[s] + h~[d]) + bias ).
// 32 lanes/node = 4 record-slots x 8 float4-feature-lanes; 8 independent
// predicated gathers in flight per window; no per-edge norm needed.
__global__ __launch_bounds__(256, 4)
void pull_kernel(const int* __restrict__ recs, const int* __restrict__ row_start,
                 const int* __restrict__ deg_arr, const float* __restrict__ h,
                 const float* __restrict__ dis, const float* __restrict__ bias,
                 float* __restrict__ out, int n, int relu_out) {
    int t = threadIdx.x;
    int node = blockIdx.x * 8 + (t >> 5);
    if (node >= n) return;
    int l32 = t & 31;
    int sub = l32 >> 3;   // record slot 0..3
    int fb = l32 & 7;     // float4 feature block
    int start = row_start[node];
    int deg = deg_arr[node];
    const float4* h4 = (const float4*)h;
    float4 sum = make_float4(0.0f, 0.0f, 0.0f, 0.0f);
    for (int r0 = 0; r0 < deg; r0 += 32) {
#pragma unroll
        for (int w = 0; w < 8; ++w) {
            int r = r0 + w * 4 + sub;
            if (r < deg) {
                int s = recs[start + r];
                float4 v = h4[(size_t)s * 8 + fb];
                sum.x += v.x; sum.y += v.y; sum.z += v.z; sum.w += v.w;
            }
        }
    }
    sum.x += __shfl_xor(sum.x, 8, 64);  sum.y += __shfl_xor(sum.y, 8, 64);
    sum.z += __shfl_xor(sum.z, 8, 64);  sum.w += __shfl_xor(sum.w, 8, 64);
    sum.x += __shfl_xor(sum.x, 16, 64); sum.y += __shfl_xor(sum.y, 16, 64);
    sum.z += __shfl_xor(sum.z, 16, 64); sum.w += __shfl_xor(sum.w, 16, 64);
    if (sub == 0) {
        float dn = dis[node];
        float4 hv = h4[(size_t)node * 8 + fb];   // self-loop: + h~[node]
        float4 bv = ((const float4*)bias)[fb];
        float4 val;
        val.x = fmaf(dn, sum.x + hv.x, bv.x);
        val.y = fmaf(dn, sum.y + hv.y, bv.y);
        val.z = fmaf(dn, sum.z + hv.z, bv.z);
        val.w = fmaf(dn, sum.w + hv.w, bv.w);
        if (relu_out) {
            val.x = fmaxf(val.x, 0.0f); val.y = fmaxf(val.y, 0.0f);
            val.z = fmaxf(val.z, 0.0f); val.w = fmaxf(val.w, 0.0f);
        }
        ((float4*)out)[(size_t)node * 8 + fb] = val;
    }
}

extern "C" void kernel_launch(void* const* d_in, const int* in_sizes, int n_in,
                              void* d_out, int out_size, void* d_ws, size_t ws_size,
                              hipStream_t stream) {
    const float* x = (const float*)d_in[0];
    const void* eidx_raw = d_in[1];
    const float* W1 = (const float*)d_in[2];
    const float* b1 = (const float*)d_in[3];
    const float* W2 = (const float*)d_in[4];
    const float* b2 = (const float*)d_in[5];
    float* out = (float*)d_out;

    const int n = in_sizes[0] / FEAT;                    // 100000
    const int e = in_sizes[1] / 2;                       // 1600000
    const int nb = (n + BIN_NODES - 1) / BIN_NODES;      // 782
    const int nblk = (e + TILE_EDGES - 1) / TILE_EDGES;  // 196
    const int M = nb * nblk;
    const int nbks = (M + 255) / 256;                    // 599 <= 1024

    // Workspace (256B-aligned). `packed` aliases `h` (dead before matmul1 writes h).
    char* ws = (char*)d_ws;
    size_t off = 0;
    auto alloc = [&](size_t bytes) { char* p = ws + off; off = (off + bytes + 255) & ~(size_t)255; return p; };
    int*   mat       = (int*)  alloc((size_t)M * 4);
    int*   bsum      = (int*)  alloc((size_t)nbks * 4);
    float* dis       = (float*)alloc((size_t)n * 4);
    int*   row_start = (int*)  alloc((size_t)n * 4);
    int*   deg       = (int*)  alloc((size_t)n * 4);
    int*   recs      = (int*)  alloc((size_t)e * 4);
    float* h         = (float*)alloc((size_t)n * FEAT * 4);
    float* acc1      = (float*)alloc((size_t)n * FEAT * 4);
    int*   packed    = (int*)h;  // e*4 = 6.4MB <= 12.8MB

    const size_t lds_bins = (size_t)(nb + 1) * 4;
    const int gNode = (n + 7) / 8;

    // CSR build (9 launches total, no global atomics)
    binA_kernel<<<nblk, 256, lds_bins, stream>>>(eidx_raw, mat, e, nb);
    scan1_kernel<<<nbks, 256, 0, stream>>>(mat, bsum, M, nb, nblk);
    scan2_kernel<<<1, 1024, 0, stream>>>(bsum, nbks);
    binC_kernel<<<nblk, 256, lds_bins, stream>>>(eidx_raw, mat, bsum, packed, e, nb, nblk);
    degsort_kernel<<<nb, 256, 0, stream>>>(packed, mat, bsum, dis, row_start, deg,
                                           recs, e, n, nb, nblk);

    // Layer 1
    matmul_kernel<<<gNode, 256, 0, stream>>>(x, W1, dis, h, n, 0);
    pull_kernel<<<gNode, 256, 0, stream>>>(recs, row_start, deg, h, dis, b1, acc1, n, 0);

    // Layer 2 (relu on read of acc1; final relu fused in writeout)
    matmul_kernel<<<gNode, 256, 0, stream>>>(acc1, W2, dis, h, n, 1);
    pull_kernel<<<gNode, 256, 0, stream>>>(recs, row_start, deg, h, dis, b2, out, n, 1);
}